// Round 1
// baseline (43.633 us; speedup 1.0000x reference)
//
#include <hip/hip_runtime.h>
#include <math.h>

#define NB 32   // batch
#define CB 32   // capsule channels C
#define KC 10   // classes
#define WHN 256 // W*H

// one block per (n,c); 256 threads, one per spatial position
__global__ __launch_bounds__(256) void caps_main(
    const float* __restrict__ l,      // (N,C,16,16,16)
    const float* __restrict__ g,      // (N,10,16)
    const float* __restrict__ weight, // (C,10,4,4)
    const float* __restrict__ v0,     // (N,10,16) or unused
    const float* __restrict__ v1,     // (N,10,16) or unused
    float* __restrict__ s_out,        // (N,10,16) atomically accumulated
    int nv)
{
    __shared__ __align__(16) float w_lds[KC * 16];     // w[c,k,j,l]
    __shared__ __align__(16) float E_lds[KC * 16];     // E[k][i][j]
    __shared__ __align__(16) float lr_lds[256 * 17];   // lr[m][ij], padded
    __shared__ __align__(16) float c_lds[KC * 260];    // c[k][m], padded
    __shared__ __align__(16) float T_lds[KC * 16];     // T[k][ij]

    const int tid = threadIdx.x;
    const int blk = blockIdx.x;
    const int n = blk >> 5;
    const int c = blk & 31;

    // stage weights for this channel c
    if (tid < KC * 16) w_lds[tid] = weight[c * 160 + tid];
    __syncthreads();

    // E[k][i][j] = sum_l (g[n,k,i*4+l] + v0[..] + v1[..]) * w[c,k,j,l]
    if (tid < KC * 16) {
        const int k = tid >> 4;
        const int i = (tid >> 2) & 3;
        const int j = tid & 3;
        const float* gv = g + (n * KC + k) * 16;
        const float* wv0 = v0 + (n * KC + k) * 16;
        const float* wv1 = v1 + (n * KC + k) * 16;
        const float* wk = w_lds + k * 16;
        float e = 0.f;
        #pragma unroll
        for (int ll = 0; ll < 4; ++ll) {
            float aeff = gv[i * 4 + ll];
            if (nv > 0) aeff += wv0[i * 4 + ll];
            if (nv > 1) aeff += wv1[i * 4 + ll];
            e = fmaf(aeff, wk[j * 4 + ll], e);
        }
        E_lds[tid] = e;
    }

    // load this thread's 4x4 pose matrix lr[ij] = l[n,c,ij,x,y]; coalesced over tid
    float lr[16];
    const float* lbase = l + (size_t)(n * CB + c) * 4096 + tid;
    #pragma unroll
    for (int ij = 0; ij < 16; ++ij) {
        lr[ij] = lbase[ij * 256];
        lr_lds[tid * 17 + ij] = lr[ij];
    }
    __syncthreads();

    // b[k] = lr . E[k]  (replays b0 + all previous routing updates)
    float b[KC];
    #pragma unroll
    for (int k = 0; k < KC; ++k) {
        const float4* e4 = (const float4*)(E_lds + k * 16);
        float4 e0 = e4[0], e1 = e4[1], e2 = e4[2], e3 = e4[3];
        float acc = 0.f;
        acc = fmaf(lr[0], e0.x, acc);  acc = fmaf(lr[1], e0.y, acc);
        acc = fmaf(lr[2], e0.z, acc);  acc = fmaf(lr[3], e0.w, acc);
        acc = fmaf(lr[4], e1.x, acc);  acc = fmaf(lr[5], e1.y, acc);
        acc = fmaf(lr[6], e1.z, acc);  acc = fmaf(lr[7], e1.w, acc);
        acc = fmaf(lr[8], e2.x, acc);  acc = fmaf(lr[9], e2.y, acc);
        acc = fmaf(lr[10], e2.z, acc); acc = fmaf(lr[11], e2.w, acc);
        acc = fmaf(lr[12], e3.x, acc); acc = fmaf(lr[13], e3.y, acc);
        acc = fmaf(lr[14], e3.z, acc); acc = fmaf(lr[15], e3.w, acc);
        b[k] = acc;
    }

    // softmax over k (10 classes)
    float mx = b[0];
    #pragma unroll
    for (int k = 1; k < KC; ++k) mx = fmaxf(mx, b[k]);
    float sum = 0.f;
    #pragma unroll
    for (int k = 0; k < KC; ++k) { b[k] = __expf(b[k] - mx); sum += b[k]; }
    const float inv = 1.f / sum;
    #pragma unroll
    for (int k = 0; k < KC; ++k) c_lds[k * 260 + tid] = b[k] * inv;
    __syncthreads();

    // T[k][ij] = sum_m c[k][m] * lr[m][ij]   (160 threads, 256-term dots)
    if (tid < KC * 16) {
        const int k = tid >> 4;
        const int ij = tid & 15;
        const float* cp = c_lds + k * 260;
        const float* lp = lr_lds + ij;
        float t = 0.f;
        #pragma unroll 8
        for (int m = 0; m < 256; ++m)
            t = fmaf(cp[m], lp[m * 17], t);
        T_lds[tid] = t;
    }
    __syncthreads();

    // s[n,k,i*4+l] += sum_j T[k][i*4+j] * w[k][j*4+l]
    if (tid < KC * 16) {
        const int k = tid >> 4;
        const int i = (tid >> 2) & 3;
        const int ll = tid & 3;
        float sv = 0.f;
        #pragma unroll
        for (int j = 0; j < 4; ++j)
            sv = fmaf(T_lds[k * 16 + i * 4 + j], w_lds[k * 16 + j * 4 + ll], sv);
        atomicAdd(&s_out[(n * KC + k) * 16 + i * 4 + ll], sv);
    }
}

// squash s -> v; if a_out != nullptr also produce activation a = sigmoid(||v||)
__global__ void caps_squash(const float* __restrict__ s,
                            float* __restrict__ v_out,
                            float* __restrict__ a_out)
{
    const int idx = blockIdx.x * blockDim.x + threadIdx.x;  // n*10+k
    if (idx >= NB * KC) return;
    const float* sp = s + idx * 16;
    float sv[16];
    float sq = 0.f;
    #pragma unroll
    for (int d = 0; d < 16; ++d) { sv[d] = sp[d]; sq = fmaf(sv[d], sv[d], sq); }
    sq = fmaxf(sq, 1e-30f);
    const float scale = sq / ((1.f + sq) * sqrtf(sq));
    float* vp = v_out + idx * 16;
    #pragma unroll
    for (int d = 0; d < 16; ++d) vp[d] = sv[d] * scale;
    if (a_out) {
        const float nrm = sq / (1.f + sq);           // = ||v||
        a_out[idx] = 1.f / (1.f + __expf(-nrm));
    }
}

extern "C" void kernel_launch(void* const* d_in, const int* in_sizes, int n_in,
                              void* d_out, int out_size, void* d_ws, size_t ws_size,
                              hipStream_t stream) {
    const float* l = (const float*)d_in[0];
    const float* g = (const float*)d_in[1];
    const float* w = (const float*)d_in[2];
    float* out = (float*)d_out;
    float* ws = (float*)d_ws;

    float* s0 = ws;            // 5120 floats each
    float* s1 = ws + 5120;
    float* s2 = ws + 10240;
    float* v0 = ws + 15360;
    float* v1 = ws + 20480;

    // zero the three s accumulators (must happen every call; ws is not re-poisoned)
    hipMemsetAsync(ws, 0, 3 * 5120 * sizeof(float), stream);

    // routing iteration 0: b = g.V
    caps_main<<<dim3(NB * CB), dim3(256), 0, stream>>>(l, g, w, v0, v1, s0, 0);
    caps_squash<<<dim3(5), dim3(64), 0, stream>>>(s0, v0, nullptr);

    // iteration 1: b = g.V + V.v0
    caps_main<<<dim3(NB * CB), dim3(256), 0, stream>>>(l, g, w, v0, v1, s1, 1);
    caps_squash<<<dim3(5), dim3(64), 0, stream>>>(s1, v1, nullptr);

    // iteration 2: b = g.V + V.v0 + V.v1
    caps_main<<<dim3(NB * CB), dim3(256), 0, stream>>>(l, g, w, v0, v1, s2, 2);
    // final squash writes outputs: a (320) then v (5120)
    caps_squash<<<dim3(5), dim3(64), 0, stream>>>(s2, out + 320, out);
}

// Round 2
// 29.031 us; speedup vs baseline: 1.5030x; 1.5030x over previous
//
#include <hip/hip_runtime.h>
#include <math.h>

#define NB 32   // batch
#define CB 32   // capsule channels C
#define KC 10   // classes
#define PAD_LRT 260  // floats per lrT row (16B-aligned, optimal b128 banking)
#define PAD_TP  168  // floats per Tp row (2-way = free banking)

// one block per (n,c); 256 threads, one per spatial position m
__global__ __launch_bounds__(256) void caps_main(
    const float* __restrict__ l,      // (N,C,16,16,16)
    const float* __restrict__ g,      // (N,10,16)
    const float* __restrict__ weight, // (C,10,4,4)
    const float* __restrict__ sp0,    // s_part from iter 0 (N,C,160) or null
    const float* __restrict__ sp1,    // s_part from iter 1 (N,C,160) or null
    float* __restrict__ s_out,        // s_part out (N,C,160)
    int nv)
{
    __shared__ __align__(16) float w_lds[160];          // w[k,j,l]
    __shared__ __align__(16) float aeff_lds[160];       // g + v0 + v1
    __shared__ __align__(16) float E_lds[160];          // E[k][i][j]
    __shared__ __align__(16) float lrT[16 * PAD_LRT];   // lr transposed [ij][m]
    __shared__ __align__(16) float c_lds[KC * 256];     // c[k][m]
    __shared__ __align__(16) float Tp[16 * PAD_TP];     // partial T [mg][k*16+ij]
    __shared__ __align__(16) float T_lds[160];          // T[k][ij]

    const int tid = threadIdx.x;
    const int n = blockIdx.x >> 5;
    const int c = blockIdx.x & 31;

    if (tid < 160) w_lds[tid] = weight[c * 160 + tid];

    // load this thread's 4x4 pose (coalesced) and write transposed copy
    float lr[16];
    const float* lbase = l + (size_t)(n * CB + c) * 4096 + tid;
    #pragma unroll
    for (int ij = 0; ij < 16; ++ij) lr[ij] = lbase[ij * 256];
    #pragma unroll
    for (int ij = 0; ij < 16; ++ij) lrT[ij * PAD_LRT + tid] = lr[ij];

    // aeff[k][d] = g[n,k,d] + squash(sum_c sp0)[k,d] + squash(sum_c sp1)[k,d]
    if (tid < 160) {
        float a = g[n * 160 + tid];
        if (nv > 0) {
            const float* sp = sp0 + (size_t)n * (CB * 160) + tid;
            float t0 = 0.f, t1 = 0.f, t2 = 0.f, t3 = 0.f;
            #pragma unroll
            for (int cc = 0; cc < 32; cc += 4) {
                t0 += sp[cc * 160];       t1 += sp[(cc + 1) * 160];
                t2 += sp[(cc + 2) * 160]; t3 += sp[(cc + 3) * 160];
            }
            float ssum = (t0 + t1) + (t2 + t3);
            float sq = ssum * ssum;
            sq += __shfl_xor(sq, 1, 16);
            sq += __shfl_xor(sq, 2, 16);
            sq += __shfl_xor(sq, 4, 16);
            sq += __shfl_xor(sq, 8, 16);
            sq = fmaxf(sq, 1e-30f);
            a += ssum * sq / ((1.f + sq) * sqrtf(sq));
        }
        if (nv > 1) {
            const float* sp = sp1 + (size_t)n * (CB * 160) + tid;
            float t0 = 0.f, t1 = 0.f, t2 = 0.f, t3 = 0.f;
            #pragma unroll
            for (int cc = 0; cc < 32; cc += 4) {
                t0 += sp[cc * 160];       t1 += sp[(cc + 1) * 160];
                t2 += sp[(cc + 2) * 160]; t3 += sp[(cc + 3) * 160];
            }
            float ssum = (t0 + t1) + (t2 + t3);
            float sq = ssum * ssum;
            sq += __shfl_xor(sq, 1, 16);
            sq += __shfl_xor(sq, 2, 16);
            sq += __shfl_xor(sq, 4, 16);
            sq += __shfl_xor(sq, 8, 16);
            sq = fmaxf(sq, 1e-30f);
            a += ssum * sq / ((1.f + sq) * sqrtf(sq));
        }
        aeff_lds[tid] = a;
    }
    __syncthreads();

    // E[k][i][j] = sum_l aeff[k][i*4+l] * w[k][j*4+l]
    if (tid < 160) {
        const int k = tid >> 4;
        const int i = (tid >> 2) & 3;
        const int j = tid & 3;
        const float* av = aeff_lds + k * 16;
        const float* wk = w_lds + k * 16;
        float e = 0.f;
        #pragma unroll
        for (int ll = 0; ll < 4; ++ll)
            e = fmaf(av[i * 4 + ll], wk[j * 4 + ll], e);
        E_lds[tid] = e;
    }
    __syncthreads();

    // b[k] = lr . E[k]  (replays b0 + all previous routing updates), then softmax
    float b[KC];
    #pragma unroll
    for (int k = 0; k < KC; ++k) {
        const float4* e4 = (const float4*)(E_lds + k * 16);
        float4 e0 = e4[0], e1 = e4[1], e2 = e4[2], e3 = e4[3];
        float acc = 0.f;
        acc = fmaf(lr[0], e0.x, acc);  acc = fmaf(lr[1], e0.y, acc);
        acc = fmaf(lr[2], e0.z, acc);  acc = fmaf(lr[3], e0.w, acc);
        acc = fmaf(lr[4], e1.x, acc);  acc = fmaf(lr[5], e1.y, acc);
        acc = fmaf(lr[6], e1.z, acc);  acc = fmaf(lr[7], e1.w, acc);
        acc = fmaf(lr[8], e2.x, acc);  acc = fmaf(lr[9], e2.y, acc);
        acc = fmaf(lr[10], e2.z, acc); acc = fmaf(lr[11], e2.w, acc);
        acc = fmaf(lr[12], e3.x, acc); acc = fmaf(lr[13], e3.y, acc);
        acc = fmaf(lr[14], e3.z, acc); acc = fmaf(lr[15], e3.w, acc);
        b[k] = acc;
    }
    float mx = b[0];
    #pragma unroll
    for (int k = 1; k < KC; ++k) mx = fmaxf(mx, b[k]);
    float sum = 0.f;
    #pragma unroll
    for (int k = 0; k < KC; ++k) { b[k] = __expf(b[k] - mx); sum += b[k]; }
    const float inv = 1.f / sum;
    #pragma unroll
    for (int k = 0; k < KC; ++k) c_lds[k * 256 + tid] = b[k] * inv;
    __syncthreads();

    // stage 1: Tp[mg][k*16+ij] = sum_{m in 16-group mg} c[k][m] * lr[m][ij]
    {
        const int ij = tid & 15;
        const int mg = tid >> 4;
        const float4* lp = (const float4*)(lrT + ij * PAD_LRT + mg * 16);
        float4 l0 = lp[0], l1 = lp[1], l2 = lp[2], l3 = lp[3];
        #pragma unroll
        for (int k = 0; k < KC; ++k) {
            const float4* cp = (const float4*)(c_lds + k * 256 + mg * 16);
            float4 c0 = cp[0], c1 = cp[1], c2 = cp[2], c3 = cp[3];
            float t = 0.f;
            t = fmaf(c0.x, l0.x, t); t = fmaf(c0.y, l0.y, t);
            t = fmaf(c0.z, l0.z, t); t = fmaf(c0.w, l0.w, t);
            t = fmaf(c1.x, l1.x, t); t = fmaf(c1.y, l1.y, t);
            t = fmaf(c1.z, l1.z, t); t = fmaf(c1.w, l1.w, t);
            t = fmaf(c2.x, l2.x, t); t = fmaf(c2.y, l2.y, t);
            t = fmaf(c2.z, l2.z, t); t = fmaf(c2.w, l2.w, t);
            t = fmaf(c3.x, l3.x, t); t = fmaf(c3.y, l3.y, t);
            t = fmaf(c3.z, l3.z, t); t = fmaf(c3.w, l3.w, t);
            Tp[mg * PAD_TP + k * 16 + ij] = t;
        }
    }
    __syncthreads();

    // stage 2: T[k][ij] = sum_mg Tp[mg][k*16+ij]
    if (tid < 160) {
        float t = 0.f;
        #pragma unroll
        for (int mg2 = 0; mg2 < 16; ++mg2) t += Tp[mg2 * PAD_TP + tid];
        T_lds[tid] = t;
    }
    __syncthreads();

    // s_part[k][i][le] = sum_j T[k][i*4+j] * w[k][j*4+le]
    if (tid < 160) {
        const int k = tid >> 4;
        const int i = (tid >> 2) & 3;
        const int le = tid & 3;
        float sv = 0.f;
        #pragma unroll
        for (int j = 0; j < 4; ++j)
            sv = fmaf(T_lds[k * 16 + i * 4 + j], w_lds[k * 16 + j * 4 + le], sv);
        s_out[(size_t)blockIdx.x * 160 + tid] = sv;
    }
}

// final: v = squash(sum_c s_part2), a = sigmoid(||v||); writes d_out = [a | v]
__global__ __launch_bounds__(256) void caps_final(
    const float* __restrict__ sp2, float* __restrict__ out)
{
    const int idx = blockIdx.x * 256 + threadIdx.x; // 0..5119
    const int nk = idx >> 4;   // n*10+k
    const int d = idx & 15;
    const int n = nk / 10;
    const int k = nk - n * 10;
    const float* sp = sp2 + (size_t)n * (CB * 160) + k * 16 + d;
    float t0 = 0.f, t1 = 0.f, t2 = 0.f, t3 = 0.f;
    #pragma unroll
    for (int cc = 0; cc < 32; cc += 4) {
        t0 += sp[cc * 160];       t1 += sp[(cc + 1) * 160];
        t2 += sp[(cc + 2) * 160]; t3 += sp[(cc + 3) * 160];
    }
    float ssum = (t0 + t1) + (t2 + t3);
    float sq = ssum * ssum;
    sq += __shfl_xor(sq, 1, 16);
    sq += __shfl_xor(sq, 2, 16);
    sq += __shfl_xor(sq, 4, 16);
    sq += __shfl_xor(sq, 8, 16);
    sq = fmaxf(sq, 1e-30f);
    out[320 + nk * 16 + d] = ssum * sq / ((1.f + sq) * sqrtf(sq));
    if (d == 0) {
        const float nrm = sq / (1.f + sq);   // == ||v||
        out[nk] = 1.f / (1.f + __expf(-nrm));
    }
}

extern "C" void kernel_launch(void* const* d_in, const int* in_sizes, int n_in,
                              void* d_out, int out_size, void* d_ws, size_t ws_size,
                              hipStream_t stream) {
    const float* l = (const float*)d_in[0];
    const float* g = (const float*)d_in[1];
    const float* w = (const float*)d_in[2];
    float* out = (float*)d_out;
    float* ws = (float*)d_ws;

    float* s0 = ws;                 // (N,C,160) = 163840 floats each
    float* s1 = ws + 163840;
    float* s2 = ws + 327680;

    caps_main<<<dim3(NB * CB), dim3(256), 0, stream>>>(l, g, w, nullptr, nullptr, s0, 0);
    caps_main<<<dim3(NB * CB), dim3(256), 0, stream>>>(l, g, w, s0, nullptr, s1, 1);
    caps_main<<<dim3(NB * CB), dim3(256), 0, stream>>>(l, g, w, s0, s1, s2, 2);
    caps_final<<<dim3(20), dim3(256), 0, stream>>>(s2, out);
}